// Round 10
// baseline (120.668 us; speedup 1.0000x reference)
//
#include <hip/hip_runtime.h>

// ---------------- problem constants ----------------
#define N_EMB  1024
#define EMB_D  256
#define HW     1024

// d_out layout (floats)
#define OUT_ZQ      0
#define OUT_LOSS    8388608
#define OUT_PERP    8388609
#define OUT_NEAREST 8388610
#define OUT_IDX     41943042

// ws layout (bytes)
#define WS_HIST   0        // 1024*4
#define WS_ESQ    4096     // 1024*4
#define WS_LOSSP  8192     // 512*8
#define WS_EH     16384    // 1024*256*2
#define WS_TOTAL  540672

typedef unsigned long long ull;
typedef _Float16 half8 __attribute__((ext_vector_type(8)));
typedef float f32x4 __attribute__((ext_vector_type(4)));
typedef ull ull2 __attribute__((ext_vector_type(2)));

// LDS map (bytes): 38.5 KB (no B staging -> GEMM is barrier-free)
#define L_A     0        // 32KB: A f16 [64 rows][512B] swizzled; aliased as keys after gemm
#define L_ESQ   32768    // 4KB esq copy
#define L_ZSQ   36864    // 256B
#define L_WIN   37120    // 256B
#define L_RED   37376    // 2KB: zsq halves temp, later loss doubles
#define L_TOT   39424

__device__ __forceinline__ float pairwise8_combine(const float r[8]) {
    return __fadd_rn(__fadd_rn(__fadd_rn(r[0], r[1]), __fadd_rn(r[2], r[3])),
                     __fadd_rn(__fadd_rn(r[4], r[5]), __fadd_rn(r[6], r[7])));
}

// ---------------- prep: eh split (blocks 0-1023) + esq/hist (blocks 1024-1027) ----
__global__ void prep(const float* __restrict__ emb, _Float16* __restrict__ eh,
                     float* __restrict__ esq, int* __restrict__ hist) {
    int bid = blockIdx.x;
    if (bid < 1024) {
        int c = bid, k = threadIdx.x;
        eh[c * EMB_D + k] = (_Float16)emb[c * EMB_D + k];
        return;
    }
    int c = (bid - 1024) * 256 + threadIdx.x;
    const float* p = emb + (size_t)c * EMB_D;
    float tot[2];
    #pragma unroll
    for (int h = 0; h < 2; ++h) {
        float r[8];
        #pragma unroll
        for (int i = 0; i < 8; ++i) {
            float x = p[h * 128 + i];
            r[i] = __fmul_rn(x, x);
        }
        for (int k = 8; k < 128; k += 8) {
            #pragma unroll
            for (int i = 0; i < 8; ++i) {
                float x = p[h * 128 + k + i];
                r[i] = __fadd_rn(r[i], __fmul_rn(x, x));
            }
        }
        tot[h] = pairwise8_combine(r);
    }
    esq[c] = __fadd_rn(tot[0], tot[1]);
    hist[c] = 0;
}

// ---------------- fused VQ ----------------
// 512 blocks (b 32 x hw-chunk 16), 64 rows/block, 256 threads = 4 waves (2 wm x 2 wn)
__global__ __launch_bounds__(256) void fused_vq(
        const float* __restrict__ z, const float* __restrict__ emb,
        const _Float16* __restrict__ eh, const float* __restrict__ esq,
        float* __restrict__ out, int* __restrict__ hist,
        double* __restrict__ lossp) {
    __shared__ __align__(16) char lds[L_TOT];
    int t = threadIdx.x, bid = blockIdx.x;
    int b = bid >> 4, hw0 = (bid & 15) << 6;
    int lane = t & 63, wave = t >> 6;
    int wm = wave >> 1, wn = wave & 1;
    int l15 = lane & 15, lq = lane >> 4;

    // ---- P0: esq->LDS (threads 128-255); A f16 + zsq halves (threads 0-127) ----
    if (t >= 128) {
        int i = t - 128;
        #pragma unroll
        for (int q = 0; q < 2; ++q) {
            f32x4 v = *(const f32x4*)(esq + (q * 128 + i) * 4);
            *(f32x4*)(lds + L_ESQ + (q * 128 + i) * 16) = v;
        }
    } else {
        int nl = t & 63, h = (t >> 6) & 1;
        const float* zp = z + ((size_t)b << 18) + hw0 + nl;
        int kb = h << 7;                      // halfword base in row
        int abase = L_A + nl * 512;
        int sw = (nl & 7) << 4;
        float r[8];
        {   half8 hv;
            #pragma unroll
            for (int e = 0; e < 8; ++e) {
                float x = zp[(size_t)(kb + e) << 10];
                hv[e] = (_Float16)x;
                r[e] = __fmul_rn(x, x);
            }
            *(half8*)(lds + abase + (((kb << 1)) ^ sw)) = hv;
        }
        for (int c8 = 1; c8 < 16; ++c8) {
            half8 hv;
            #pragma unroll
            for (int e = 0; e < 8; ++e) {
                float x = zp[(size_t)(kb + c8 * 8 + e) << 10];
                hv[e] = (_Float16)x;
                r[e] = __fadd_rn(r[e], __fmul_rn(x, x));
            }
            *(half8*)(lds + abase + (((kb << 1) + c8 * 16) ^ sw)) = hv;
        }
        *(float*)(lds + L_RED + (h * 64 + nl) * 4) = pairwise8_combine(r);
    }
    __syncthreads();
    if (t < 64) {   // numpy: zsq = fadd(half0, half1)
        float t0 = *(float*)(lds + L_RED + t * 4);
        float t1 = *(float*)(lds + L_RED + 256 + t * 4);
        *(float*)(lds + L_ZSQ + t * 4) = __fadd_rn(t0, t1);
    }
    __syncthreads();

    // ---- A read offsets (swizzled); B is read direct from eh (L2-resident) ----
    int abase2[2], aswz[2];
    #pragma unroll
    for (int i = 0; i < 2; ++i) {
        int r = wm * 32 + i * 16 + l15;
        abase2[i] = L_A + r * 512;
        aswz[i] = (r & 7) << 4;
    }
    // lane base into eh for B frags: col = wn*64 + j*16 + l15, k = kk*32 + lq*8
    const _Float16* ehB = eh + ((size_t)(wn * 64 + l15)) * 256 + lq * 8;

    float zs[8];
    #pragma unroll
    for (int s = 0; s < 8; ++s) {
        int row = wm * 32 + (s >> 2) * 16 + lq * 4 + (s & 3);
        zs[s] = *(const float*)(lds + L_ZSQ + row * 4);
    }
    ull k1[8], k2[8];
    #pragma unroll
    for (int s = 0; s < 8; ++s) { k1[s] = ~0ULL; k2[s] = ~0ULL; }

    // ---- P1: gemm, 8 col-tiles x 8 k-chunks, NO barriers, NO LDS for B ----
    for (int cbt = 0; cbt < 8; ++cbt) {
        f32x4 acc[2][4];
        #pragma unroll
        for (int i = 0; i < 2; ++i)
            #pragma unroll
            for (int j = 0; j < 4; ++j) acc[i][j] = (f32x4){0.f, 0.f, 0.f, 0.f};

        const _Float16* ehT = ehB + (size_t)cbt * 32768;
        #pragma unroll
        for (int kk = 0; kk < 8; ++kk) {
            half8 a0 = *(const half8*)(lds + abase2[0] + ((kk * 64 + lq * 16) ^ aswz[0]));
            half8 a1 = *(const half8*)(lds + abase2[1] + ((kk * 64 + lq * 16) ^ aswz[1]));
            half8 b0 = *(const half8*)(ehT + 0 * 4096 + kk * 32);
            half8 b1 = *(const half8*)(ehT + 1 * 4096 + kk * 32);
            half8 b2 = *(const half8*)(ehT + 2 * 4096 + kk * 32);
            half8 b3 = *(const half8*)(ehT + 3 * 4096 + kk * 32);
            acc[0][0] = __builtin_amdgcn_mfma_f32_16x16x32_f16(a0, b0, acc[0][0], 0, 0, 0);
            acc[0][1] = __builtin_amdgcn_mfma_f32_16x16x32_f16(a0, b1, acc[0][1], 0, 0, 0);
            acc[0][2] = __builtin_amdgcn_mfma_f32_16x16x32_f16(a0, b2, acc[0][2], 0, 0, 0);
            acc[0][3] = __builtin_amdgcn_mfma_f32_16x16x32_f16(a0, b3, acc[0][3], 0, 0, 0);
            acc[1][0] = __builtin_amdgcn_mfma_f32_16x16x32_f16(a1, b0, acc[1][0], 0, 0, 0);
            acc[1][1] = __builtin_amdgcn_mfma_f32_16x16x32_f16(a1, b1, acc[1][1], 0, 0, 0);
            acc[1][2] = __builtin_amdgcn_mfma_f32_16x16x32_f16(a1, b2, acc[1][2], 0, 0, 0);
            acc[1][3] = __builtin_amdgcn_mfma_f32_16x16x32_f16(a1, b3, acc[1][3], 0, 0, 0);
        }

        // d = fl(fl(zs+es) - fl(2*dot)); insert into per-lane top-2
        float es[4];
        #pragma unroll
        for (int j = 0; j < 4; ++j)
            es[j] = *(const float*)(lds + L_ESQ + ((cbt << 7) + wn * 64 + j * 16 + l15) * 4);
        #pragma unroll
        for (int i = 0; i < 2; ++i)
            #pragma unroll
            for (int r = 0; r < 4; ++r) {
                const int s = i * 4 + r;
                float zsv = zs[s];
                #pragma unroll
                for (int j = 0; j < 4; ++j) {
                    float d = __fsub_rn(__fadd_rn(zsv, es[j]), __fmul_rn(2.0f, acc[i][j][r]));
                    int cg = (cbt << 7) + wn * 64 + j * 16 + l15;
                    ull key = ((ull)__float_as_uint(d) << 32) | (unsigned)cg;
                    if (key < k1[s]) { k2[s] = k1[s]; k1[s] = key; }
                    else if (key < k2[s]) { k2[s] = key; }
                }
            }
    }

    // ---- P2: keys -> LDS (alias dead A area): [row][32 slots][2] ull ----
    __syncthreads();                           // all A reads done
    #pragma unroll
    for (int s = 0; s < 8; ++s) {
        int row = wm * 32 + (s >> 2) * 16 + lq * 4 + (s & 3);
        *(ull2*)(lds + L_A + row * 512 + ((wn << 4) + l15) * 16) = (ull2){k1[s], k2[s]};
    }
    __syncthreads();

    // ---- P3/P4: per-row refine (margin 2e-4, exact fp32 slow path) + outputs ----
    for (int rr = 0; rr < 16; ++rr) {
        int row = wave * 16 + rr;
        ull k = *(const ull*)(lds + L_A + row * 512 + lane * 8);
        ull kmin = k;
        #pragma unroll
        for (int m = 1; m < 64; m <<= 1) {
            ull o = __shfl_xor(kmin, m, 64);
            kmin = o < kmin ? o : kmin;
        }
        float dmin = __uint_as_float((unsigned)(kmin >> 32));
        float dme  = __uint_as_float((unsigned)(k >> 32));
        bool cand = dme <= __fadd_rn(dmin, 2e-4f);
        ull bal = __ballot(cand);
        int winner;
        if (__popcll(bal) == 1) {
            winner = (int)(unsigned)(kmin & 0xFFFFFFFFu);   // provably exact
        } else {
            const float* zp2 = z + ((size_t)b << 18) + hw0 + row;
            float zr[4];
            #pragma unroll
            for (int e = 0; e < 4; ++e) zr[e] = zp2[(size_t)(lane + 64 * e) << 10];
            float zsr = *(const float*)(lds + L_ZSQ + row * 4);
            ull bestk = ~0ULL;
            while (bal) {
                int src = __ffsll(bal) - 1;
                bal &= bal - 1;
                ull ck = __shfl(k, src, 64);
                int c = (int)(unsigned)(ck & 0xFFFFFFFFu);
                const float* ep = emb + (size_t)c * EMB_D;
                float p = __fmul_rn(zr[3], ep[lane + 192]);
                p = __builtin_fmaf(zr[2], ep[lane + 128], p);
                p = __builtin_fmaf(zr[1], ep[lane + 64], p);
                p = __builtin_fmaf(zr[0], ep[lane], p);
                #pragma unroll
                for (int m = 1; m < 64; m <<= 1)
                    p = __fadd_rn(p, __shfl_xor(p, m, 64));
                float ec = *(const float*)(lds + L_ESQ + c * 4);
                float d = __fsub_rn(__fadd_rn(zsr, ec), __fmul_rn(2.0f, p));
                ull kk2 = ((ull)__float_as_uint(d) << 32) | (unsigned)c;
                bestk = kk2 < bestk ? kk2 : bestk;
            }
            winner = (int)(unsigned)(bestk & 0xFFFFFFFFu);
        }
        // one-hot full-row write (round-6 proven); winner is wave-uniform
        size_t n = (size_t)bid * 64 + row;
        float* np = out + OUT_NEAREST + (n << 10);
        #pragma unroll
        for (int q = 0; q < 4; ++q) {
            int c4 = q * 256 + lane * 4;
            f32x4 v = { winner == c4     ? 1.f : 0.f, winner == c4 + 1 ? 1.f : 0.f,
                        winner == c4 + 2 ? 1.f : 0.f, winner == c4 + 3 ? 1.f : 0.f };
            *(f32x4*)(np + c4) = v;
        }
        if (lane == 0) {
            out[OUT_IDX + n] = (float)winner;
            atomicAdd(&hist[winner], 1);
            *(int*)(lds + L_WIN + row * 4) = winner;
        }
    }
    __syncthreads();                           // winners ready

    // ---- P5: zq gather + straight-through + loss partial (float4 along hw) ----
    {
        int q = t & 15;                        // hw quad
        int cq = t >> 4;                       // c residue 0..15
        int4 w4 = *(const int4*)(lds + L_WIN + q * 16);
        const float* zb = z + ((size_t)b << 18) + hw0 + q * 4;
        float* ob = out + OUT_ZQ + ((size_t)b << 18) + hw0 + q * 4;
        double s = 0.0;
        for (int i = 0; i < 16; ++i) {
            int c = cq + (i << 4);
            f32x4 zc = *(const f32x4*)(zb + ((size_t)c << 10));
            f32x4 ev = { emb[(size_t)w4.x * EMB_D + c], emb[(size_t)w4.y * EMB_D + c],
                         emb[(size_t)w4.z * EMB_D + c], emb[(size_t)w4.w * EMB_D + c] };
            f32x4 df = { __fsub_rn(ev[0], zc[0]), __fsub_rn(ev[1], zc[1]),
                         __fsub_rn(ev[2], zc[2]), __fsub_rn(ev[3], zc[3]) };
            f32x4 st = { __fadd_rn(zc[0], df[0]), __fadd_rn(zc[1], df[1]),
                         __fadd_rn(zc[2], df[2]), __fadd_rn(zc[3], df[3]) };
            *(f32x4*)(ob + ((size_t)c << 10)) = st;
            s += (double)__fmul_rn(df[0], df[0]) + (double)__fmul_rn(df[1], df[1])
               + (double)__fmul_rn(df[2], df[2]) + (double)__fmul_rn(df[3], df[3]);
        }
        *(double*)(lds + L_RED + t * 8) = s;
        __syncthreads();
        for (int st = 128; st > 0; st >>= 1) {
            if (t < st) {
                double o = *(double*)(lds + L_RED + (t + st) * 8);
                *(double*)(lds + L_RED + t * 8) += o;
            }
            __syncthreads();
        }
        if (t == 0) lossp[bid] = *(double*)(lds + L_RED);
    }
}

// ---------------- scalars ----------------
__global__ void finalize_scalars(const double* __restrict__ lossp,
                                 const int* __restrict__ hist,
                                 float* __restrict__ out_loss,
                                 float* __restrict__ out_perp) {
    __shared__ double sd[1024];
    int t = threadIdx.x;

    sd[t] = (t < 512) ? lossp[t] : 0.0;
    __syncthreads();
    for (int st = 512; st > 0; st >>= 1) {
        if (t < st) sd[t] += sd[t + st];
        __syncthreads();
    }
    if (t == 0) {
        double loss = 1.25 * (sd[0] / 8388608.0);
        *out_loss = (float)loss;
    }
    __syncthreads();

    float p = (float)hist[t] * (1.0f / 32768.0f);
    float term = __fmul_rn(p, logf(__fadd_rn(p, 1e-10f)));
    sd[t] = (double)term;
    __syncthreads();
    for (int st = 512; st > 0; st >>= 1) {
        if (t < st) sd[t] += sd[t + st];
        __syncthreads();
    }
    if (t == 0) *out_perp = expf(-(float)sd[0]);
}

// ---------------- launch ----------------
extern "C" void kernel_launch(void* const* d_in, const int* in_sizes, int n_in,
                              void* d_out, int out_size, void* d_ws, size_t ws_size,
                              hipStream_t stream) {
    const float* z   = (const float*)d_in[0];
    const float* emb = (const float*)d_in[1];
    float* out = (float*)d_out;
    char*  ws  = (char*)d_ws;

    int*      hist  = (int*)(ws + WS_HIST);
    float*    esq   = (float*)(ws + WS_ESQ);
    double*   lossp = (double*)(ws + WS_LOSSP);
    _Float16* eh    = (_Float16*)(ws + WS_EH);

    prep<<<1028, 256, 0, stream>>>(emb, eh, esq, hist);
    fused_vq<<<512, 256, 0, stream>>>(z, emb, eh, esq, out, hist, lossp);
    finalize_scalars<<<1, 1024, 0, stream>>>(lossp, hist,
                                             out + OUT_LOSS, out + OUT_PERP);
}

// Round 11
// 82.083 us; speedup vs baseline: 1.4701x; 1.4701x over previous
//
#include <hip/hip_runtime.h>

// ---------------- problem constants ----------------
#define N_EMB  1024
#define EMB_D  256
#define HW     1024

// d_out layout (floats)
#define OUT_ZQ      0
#define OUT_LOSS    8388608
#define OUT_PERP    8388609
#define OUT_NEAREST 8388610
#define OUT_IDX     41943042

// ws layout (bytes)
#define WS_HIST   0        // 1024*4
#define WS_ESQ    4096     // 1024*4
#define WS_LOSSP  8192     // 1024*8
#define WS_EH     16384    // 1024*256*2
#define WS_TOTAL  540672

typedef unsigned long long ull;
typedef _Float16 half8 __attribute__((ext_vector_type(8)));
typedef float f32x4 __attribute__((ext_vector_type(4)));
typedef ull ull2 __attribute__((ext_vector_type(2)));

// LDS map (bytes): 38.3 KB -> 4 blocks/CU (the whole point of this round)
#define L_A     0        // 16KB: A f16 [32 rows][512B] swizzled; aliased as keys after gemm
#define L_B     16384    // 16KB: single-buffer B tile [128 cols][128B] swizzled
#define L_ESQ   32768    // 4KB esq copy
#define L_ZSQ   36864    // 128B
#define L_WIN   36992    // 128B
#define L_RED   37120    // 2KB: zsq halves temp, later loss doubles
#define L_TOT   39168

__device__ __forceinline__ void gload16(const void* g, void* l) {
    __builtin_amdgcn_global_load_lds(
        (const __attribute__((address_space(1))) unsigned int*)g,
        (__attribute__((address_space(3))) unsigned int*)l, 16, 0, 0);
}

__device__ __forceinline__ float pairwise8_combine(const float r[8]) {
    return __fadd_rn(__fadd_rn(__fadd_rn(r[0], r[1]), __fadd_rn(r[2], r[3])),
                     __fadd_rn(__fadd_rn(r[4], r[5]), __fadd_rn(r[6], r[7])));
}

// ---------------- prep: eh split (blocks 0-1023) + esq/hist (blocks 1024-1027) ----
__global__ void prep(const float* __restrict__ emb, _Float16* __restrict__ eh,
                     float* __restrict__ esq, int* __restrict__ hist) {
    int bid = blockIdx.x;
    if (bid < 1024) {
        int c = bid, k = threadIdx.x;
        eh[c * EMB_D + k] = (_Float16)emb[c * EMB_D + k];
        return;
    }
    int c = (bid - 1024) * 256 + threadIdx.x;
    const float* p = emb + (size_t)c * EMB_D;
    float tot[2];
    #pragma unroll
    for (int h = 0; h < 2; ++h) {
        float r[8];
        #pragma unroll
        for (int i = 0; i < 8; ++i) {
            float x = p[h * 128 + i];
            r[i] = __fmul_rn(x, x);
        }
        for (int k = 8; k < 128; k += 8) {
            #pragma unroll
            for (int i = 0; i < 8; ++i) {
                float x = p[h * 128 + k + i];
                r[i] = __fadd_rn(r[i], __fmul_rn(x, x));
            }
        }
        tot[h] = pairwise8_combine(r);
    }
    esq[c] = __fadd_rn(tot[0], tot[1]);
    hist[c] = 0;
}

// ---------------- fused VQ ----------------
// 1024 blocks (b 32 x hw-chunk 32), 32 rows/block, 256 threads = 4 waves (2 wm x 2 wn)
// 38.3KB LDS -> 4 blocks/CU: cross-block overlap of GEMM / store / load phases.
__global__ __launch_bounds__(256, 4) void fused_vq(
        const float* __restrict__ z, const float* __restrict__ emb,
        const _Float16* __restrict__ eh, const float* __restrict__ esq,
        float* __restrict__ out, int* __restrict__ hist,
        double* __restrict__ lossp) {
    __shared__ __align__(16) char lds[L_TOT];
    int t = threadIdx.x, bid = blockIdx.x;
    int b = bid >> 5, hw0 = (bid & 31) << 5;
    int lane = t & 63, wave = t >> 6;
    int wm = wave >> 1, wn = wave & 1;
    int l15 = lane & 15, lq = lane >> 4;

    // ---- P0: A f16 + zsq halves (threads 0-63); esq->LDS (threads 128-255) ----
    if (t < 64) {
        int nl = t & 31, h = (t >> 5) & 1;
        const float* zp = z + ((size_t)b << 18) + hw0 + nl;
        int kb = h << 7;                      // halfword base in row
        int abase = L_A + nl * 512;
        int sw = (nl & 7) << 4;
        float r[8];
        {   half8 hv;
            #pragma unroll
            for (int e = 0; e < 8; ++e) {
                float x = zp[(size_t)(kb + e) << 10];
                hv[e] = (_Float16)x;
                r[e] = __fmul_rn(x, x);
            }
            *(half8*)(lds + abase + (((kb << 1)) ^ sw)) = hv;
        }
        for (int c8 = 1; c8 < 16; ++c8) {
            half8 hv;
            #pragma unroll
            for (int e = 0; e < 8; ++e) {
                float x = zp[(size_t)(kb + c8 * 8 + e) << 10];
                hv[e] = (_Float16)x;
                r[e] = __fadd_rn(r[e], __fmul_rn(x, x));
            }
            *(half8*)(lds + abase + (((kb << 1) + c8 * 16) ^ sw)) = hv;
        }
        *(float*)(lds + L_RED + (h * 32 + nl) * 4) = pairwise8_combine(r);
    } else if (t >= 128) {
        int i = t - 128;
        #pragma unroll
        for (int q = 0; q < 2; ++q) {
            f32x4 v = *(const f32x4*)(esq + (q * 128 + i) * 4);
            *(f32x4*)(lds + L_ESQ + (q * 128 + i) * 16) = v;
        }
    }
    __syncthreads();
    if (t < 32) {   // numpy: zsq = fadd(half0, half1)
        float t0 = *(float*)(lds + L_RED + t * 4);
        float t1 = *(float*)(lds + L_RED + 128 + t * 4);
        *(float*)(lds + L_ZSQ + t * 4) = __fadd_rn(t0, t1);
    }
    __syncthreads();

    // ---- read offsets (identical addressing algebra to the validated round-6) ----
    int aoffs[2], boffs[4][2];
    {
        int r = wm * 16 + l15;
        #pragma unroll
        for (int kc = 0; kc < 2; ++kc)
            aoffs[kc] = L_A + r * 512 + ((kc * 64 + lq * 16) ^ ((r & 7) << 4));
    }
    #pragma unroll
    for (int j = 0; j < 4; ++j) {
        int c = wn * 64 + j * 16 + l15;
        #pragma unroll
        for (int kc = 0; kc < 2; ++kc)
            boffs[j][kc] = L_B + c * 128 + ((kc * 64 + lq * 16) ^ ((c & 7) << 4));
    }
    int bsrc[4], bdst[4];
    #pragma unroll
    for (int is = 0; is < 4; ++is) {
        int o = is * 4096 + t * 16;
        int col = o >> 7;
        int K = (o & 127) ^ ((col & 7) << 4);
        bsrc[is] = col * 256 + (K >> 1);      // halfword offset within eh col-block
        bdst[is] = L_B + o;
    }
    float zs[4];
    #pragma unroll
    for (int s = 0; s < 4; ++s)
        zs[s] = *(const float*)(lds + L_ZSQ + (wm * 16 + lq * 4 + s) * 4);
    ull k1[4], k2[4];
    #pragma unroll
    for (int s = 0; s < 4; ++s) { k1[s] = ~0ULL; k2[s] = ~0ULL; }

    // ---- P1: gemm, 8 col-tiles x 4 k-steps (round-6 proven 2-barrier rounds) ----
    for (int cbt = 0; cbt < 8; ++cbt) {
        f32x4 acc[4];
        #pragma unroll
        for (int j = 0; j < 4; ++j) acc[j] = (f32x4){0.f, 0.f, 0.f, 0.f};

        for (int kt = 0; kt < 4; ++kt) {
            __syncthreads();                   // prev tile fully consumed
            #pragma unroll
            for (int is = 0; is < 4; ++is)
                gload16(eh + cbt * 32768 + kt * 64 + bsrc[is], lds + bdst[is]);
            __syncthreads();                   // staged B visible (vmcnt drained)

            half8 a0 = *(const half8*)(lds + aoffs[0] + kt * 128);
            half8 a1 = *(const half8*)(lds + aoffs[1] + kt * 128);
            half8 bb[4][2];
            #pragma unroll
            for (int j = 0; j < 4; ++j) {
                bb[j][0] = *(const half8*)(lds + boffs[j][0]);
                bb[j][1] = *(const half8*)(lds + boffs[j][1]);
            }
            #pragma unroll
            for (int j = 0; j < 4; ++j) {
                acc[j] = __builtin_amdgcn_mfma_f32_16x16x32_f16(a0, bb[j][0], acc[j], 0, 0, 0);
                acc[j] = __builtin_amdgcn_mfma_f32_16x16x32_f16(a1, bb[j][1], acc[j], 0, 0, 0);
            }
        }
        // d = fl(fl(zs+es) - fl(2*dot)); insert into per-lane top-2
        float es[4];
        #pragma unroll
        for (int j = 0; j < 4; ++j)
            es[j] = *(const float*)(lds + L_ESQ + ((cbt << 7) + wn * 64 + j * 16 + l15) * 4);
        #pragma unroll
        for (int s = 0; s < 4; ++s) {
            float zsv = zs[s];
            #pragma unroll
            for (int j = 0; j < 4; ++j) {
                float d = __fsub_rn(__fadd_rn(zsv, es[j]), __fmul_rn(2.0f, acc[j][s]));
                int cg = (cbt << 7) + wn * 64 + j * 16 + l15;
                ull key = ((ull)__float_as_uint(d) << 32) | (unsigned)cg;
                if (key < k1[s]) { k2[s] = k1[s]; k1[s] = key; }
                else if (key < k2[s]) { k2[s] = key; }
            }
        }
    }

    // ---- P2: keys -> LDS (alias dead A area): [row][32 slots][2] ull ----
    __syncthreads();                           // all A reads done
    #pragma unroll
    for (int s = 0; s < 4; ++s) {
        int row = wm * 16 + lq * 4 + s;
        *(ull2*)(lds + L_A + row * 512 + ((wn << 4) + l15) * 16) = (ull2){k1[s], k2[s]};
    }
    __syncthreads();

    // ---- P3/P4: per-row refine (margin 2e-4, exact fp32 slow path) + outputs ----
    for (int rr = 0; rr < 8; ++rr) {
        int row = wave * 8 + rr;
        ull k = *(const ull*)(lds + L_A + row * 512 + lane * 8);
        ull kmin = k;
        #pragma unroll
        for (int m = 1; m < 64; m <<= 1) {
            ull o = __shfl_xor(kmin, m, 64);
            kmin = o < kmin ? o : kmin;
        }
        float dmin = __uint_as_float((unsigned)(kmin >> 32));
        float dme  = __uint_as_float((unsigned)(k >> 32));
        bool cand = dme <= __fadd_rn(dmin, 2e-4f);
        ull bal = __ballot(cand);
        int winner;
        if (__popcll(bal) == 1) {
            winner = (int)(unsigned)(kmin & 0xFFFFFFFFu);   // provably exact
        } else {
            const float* zp2 = z + ((size_t)b << 18) + hw0 + row;
            float zr[4];
            #pragma unroll
            for (int e = 0; e < 4; ++e) zr[e] = zp2[(size_t)(lane + 64 * e) << 10];
            float zsr = *(const float*)(lds + L_ZSQ + row * 4);
            ull bestk = ~0ULL;
            while (bal) {
                int src = __ffsll(bal) - 1;
                bal &= bal - 1;
                ull ck = __shfl(k, src, 64);
                int c = (int)(unsigned)(ck & 0xFFFFFFFFu);
                const float* ep = emb + (size_t)c * EMB_D;
                float p = __fmul_rn(zr[3], ep[lane + 192]);
                p = __builtin_fmaf(zr[2], ep[lane + 128], p);
                p = __builtin_fmaf(zr[1], ep[lane + 64], p);
                p = __builtin_fmaf(zr[0], ep[lane], p);
                #pragma unroll
                for (int m = 1; m < 64; m <<= 1)
                    p = __fadd_rn(p, __shfl_xor(p, m, 64));
                float ec = *(const float*)(lds + L_ESQ + c * 4);
                float d = __fsub_rn(__fadd_rn(zsr, ec), __fmul_rn(2.0f, p));
                ull kk2 = ((ull)__float_as_uint(d) << 32) | (unsigned)c;
                bestk = kk2 < bestk ? kk2 : bestk;
            }
            winner = (int)(unsigned)(bestk & 0xFFFFFFFFu);
        }
        // one-hot full-row write (round-6 proven); winner is wave-uniform
        size_t n = (size_t)bid * 32 + row;
        float* np = out + OUT_NEAREST + (n << 10);
        #pragma unroll
        for (int q = 0; q < 4; ++q) {
            int c4 = q * 256 + lane * 4;
            f32x4 v = { winner == c4     ? 1.f : 0.f, winner == c4 + 1 ? 1.f : 0.f,
                        winner == c4 + 2 ? 1.f : 0.f, winner == c4 + 3 ? 1.f : 0.f };
            *(f32x4*)(np + c4) = v;
        }
        if (lane == 0) {
            out[OUT_IDX + n] = (float)winner;
            atomicAdd(&hist[winner], 1);
            *(int*)(lds + L_WIN + row * 4) = winner;
        }
    }
    __syncthreads();                           // winners ready

    // ---- P5: zq gather + straight-through + loss partial (float4 along hw) ----
    {
        int q = t & 7;                         // hw quad (8 quads x 4 = 32 hw)
        int cq = t >> 3;                       // c residue 0..31
        int4 w4 = *(const int4*)(lds + L_WIN + q * 16);
        const float* zb = z + ((size_t)b << 18) + hw0 + q * 4;
        float* ob = out + OUT_ZQ + ((size_t)b << 18) + hw0 + q * 4;
        double s = 0.0;
        #pragma unroll
        for (int i = 0; i < 8; ++i) {
            int c = cq + (i << 5);
            f32x4 zc = *(const f32x4*)(zb + ((size_t)c << 10));
            f32x4 ev = { emb[(size_t)w4.x * EMB_D + c], emb[(size_t)w4.y * EMB_D + c],
                         emb[(size_t)w4.z * EMB_D + c], emb[(size_t)w4.w * EMB_D + c] };
            f32x4 df = { __fsub_rn(ev[0], zc[0]), __fsub_rn(ev[1], zc[1]),
                         __fsub_rn(ev[2], zc[2]), __fsub_rn(ev[3], zc[3]) };
            f32x4 st = { __fadd_rn(zc[0], df[0]), __fadd_rn(zc[1], df[1]),
                         __fadd_rn(zc[2], df[2]), __fadd_rn(zc[3], df[3]) };
            *(f32x4*)(ob + ((size_t)c << 10)) = st;
            s += (double)__fmul_rn(df[0], df[0]) + (double)__fmul_rn(df[1], df[1])
               + (double)__fmul_rn(df[2], df[2]) + (double)__fmul_rn(df[3], df[3]);
        }
        *(double*)(lds + L_RED + t * 8) = s;
        __syncthreads();
        for (int st = 128; st > 0; st >>= 1) {
            if (t < st) {
                double o = *(double*)(lds + L_RED + (t + st) * 8);
                *(double*)(lds + L_RED + t * 8) += o;
            }
            __syncthreads();
        }
        if (t == 0) lossp[bid] = *(double*)(lds + L_RED);
    }
}

// ---------------- scalars ----------------
__global__ void finalize_scalars(const double* __restrict__ lossp,
                                 const int* __restrict__ hist,
                                 float* __restrict__ out_loss,
                                 float* __restrict__ out_perp) {
    __shared__ double sd[1024];
    int t = threadIdx.x;

    sd[t] = lossp[t];
    __syncthreads();
    for (int st = 512; st > 0; st >>= 1) {
        if (t < st) sd[t] += sd[t + st];
        __syncthreads();
    }
    if (t == 0) {
        double loss = 1.25 * (sd[0] / 8388608.0);
        *out_loss = (float)loss;
    }
    __syncthreads();

    float p = (float)hist[t] * (1.0f / 32768.0f);
    float term = __fmul_rn(p, logf(__fadd_rn(p, 1e-10f)));
    sd[t] = (double)term;
    __syncthreads();
    for (int st = 512; st > 0; st >>= 1) {
        if (t < st) sd[t] += sd[t + st];
        __syncthreads();
    }
    if (t == 0) *out_perp = expf(-(float)sd[0]);
}

// ---------------- launch ----------------
extern "C" void kernel_launch(void* const* d_in, const int* in_sizes, int n_in,
                              void* d_out, int out_size, void* d_ws, size_t ws_size,
                              hipStream_t stream) {
    const float* z   = (const float*)d_in[0];
    const float* emb = (const float*)d_in[1];
    float* out = (float*)d_out;
    char*  ws  = (char*)d_ws;

    int*      hist  = (int*)(ws + WS_HIST);
    float*    esq   = (float*)(ws + WS_ESQ);
    double*   lossp = (double*)(ws + WS_LOSSP);
    _Float16* eh    = (_Float16*)(ws + WS_EH);

    prep<<<1028, 256, 0, stream>>>(emb, eh, esq, hist);
    fused_vq<<<1024, 256, 0, stream>>>(z, emb, eh, esq, out, hist, lossp);
    finalize_scalars<<<1, 1024, 0, stream>>>(lossp, hist,
                                             out + OUT_LOSS, out + OUT_PERP);
}